// Round 17
// baseline (2963.386 us; speedup 1.0000x reference)
//
#include <hip/hip_runtime.h>
#include <math.h>

#define BB 64      // batch
#define SS 512     // seq len
#define EE 128     // embed dim
#define HH 256     // hidden
#define NC 9       // classes
#define G4 1024    // 4*H gates (one direction)
#define TCLOG 7
#define TC 128     // time chunk
#define NCH (SS / TC)

#define KLQ 9      // k16 chunks (of 16 k) cached in LDS = 144 KB (int8)
// streamed: kc in [KLQ, 16) = 7 chunks = 112 KB/step

typedef _Float16 half2v __attribute__((ext_vector_type(2)));

// ---------- activations (overflow-safe, fast) ----------
__device__ __forceinline__ float sigf(float x) {
    return 1.0f / (1.0f + __expf(-x));
}
__device__ __forceinline__ float tanhfast(float x) {
    float a = fabsf(x);
    float e = __expf(-2.0f * a);
    float t = (1.0f - e) / (1.0f + e);
    return copysignf(t, x);
}
// 8 f16 MACs via 4x v_dot2_f32_f16 (f32 accumulate)
__device__ __forceinline__ float dot8h(uint4 w, uint4 h, float acc) {
    acc = __builtin_amdgcn_fdot2(__builtin_bit_cast(half2v, w.x),
                                 __builtin_bit_cast(half2v, h.x), acc, false);
    acc = __builtin_amdgcn_fdot2(__builtin_bit_cast(half2v, w.y),
                                 __builtin_bit_cast(half2v, h.y), acc, false);
    acc = __builtin_amdgcn_fdot2(__builtin_bit_cast(half2v, w.z),
                                 __builtin_bit_cast(half2v, h.z), acc, false);
    acc = __builtin_amdgcn_fdot2(__builtin_bit_cast(half2v, w.w),
                                 __builtin_bit_cast(half2v, h.w), acc, false);
    return acc;
}
// 16 i8 MACs via 4x v_dot4_i32_i8 (exact int32 accumulate)
__device__ __forceinline__ int dot16q(uint4 w, uint4 h, int acc) {
    acc = __builtin_amdgcn_sdot4((int)w.x, (int)h.x, acc, false);
    acc = __builtin_amdgcn_sdot4((int)w.y, (int)h.y, acc, false);
    acc = __builtin_amdgcn_sdot4((int)w.z, (int)h.z, acc, false);
    acc = __builtin_amdgcn_sdot4((int)w.w, (int)h.w, acc, false);
    return acc;
}
__device__ __forceinline__ ushort f16b(float x) {
    return __builtin_bit_cast(ushort, (_Float16)x);
}

// ---------- per-row int8 quantize + transpose, THREAD-ORDER layout ----------
// wTq[dir][kc][tidx][4] where tidx = (col<<2)|q for gate row j = q*256+col.
// grid 2048 blocks (row = dir*1024+j), 64 threads (1 wave)
__global__ void quant_whh(const float* __restrict__ whh, uint* __restrict__ wTq,
                          float* __restrict__ swf) {
    const int row = blockIdx.x;        // 0..2047
    const int t = threadIdx.x;         // 0..63, owns k = 4t..4t+3
    float4 v = *(const float4*)(whh + (long)row * 256 + t * 4);
    float mx = fmaxf(fmaxf(fabsf(v.x), fabsf(v.y)), fmaxf(fabsf(v.z), fabsf(v.w)));
    #pragma unroll
    for (int o = 32; o > 0; o >>= 1) mx = fmaxf(mx, __shfl_xor(mx, o));
    float inv = (mx > 0.f) ? 127.f / mx : 0.f;
    int q0 = (int)rintf(v.x * inv) & 255;
    int q1 = (int)rintf(v.y * inv) & 255;
    int q2 = (int)rintf(v.z * inv) & 255;
    int q3 = (int)rintf(v.w * inv) & 255;
    uint u = (uint)q0 | ((uint)q1 << 8) | ((uint)q2 << 16) | ((uint)q3 << 24);
    const int dir = row >> 10, j = row & 1023;
    const int kc = t >> 2, l4 = t & 3;
    const int tidx = ((j & 255) << 2) | (j >> 8);      // thread-order
    wTq[(((long)(dir * 16 + kc) * 1024 + tidx) << 2) + l4] = u;
    if (t == 0) swf[row] = (mx > 0.f) ? (mx / 127.f) * (1.f / 127.f) : 0.f;
}

// ---------- plain f16 pack (row-major, n % 8 == 0) ----------
__global__ void pack_f16(const float* __restrict__ in, ushort* __restrict__ out, int n8) {
    int i = blockIdx.x * 256 + threadIdx.x;
    if (i >= n8) return;
    float4 a = *(const float4*)(in + (long)i * 8);
    float4 b = *(const float4*)(in + (long)i * 8 + 4);
    _Float16 o[8] = {(_Float16)a.x, (_Float16)a.y, (_Float16)a.z, (_Float16)a.w,
                     (_Float16)b.x, (_Float16)b.y, (_Float16)b.z, (_Float16)b.w};
    *(uint4*)(out + (long)i * 8) = *(uint4*)o;
}

// ---------- f16 xg GEMM v2: BM=BN=128, 8x8 microtile, 256 threads ----------
// LDS reuse 4 dots/uint4-read (2x round-15); row+(row>>3) pad kills 4-way conflict.
template <int KDIM, bool GATHER>
__global__ __launch_bounds__(256, 2) void gemm_xg16b(
    const void* __restrict__ Av, const int* __restrict__ tokens,
    const ushort* __restrict__ Wh,      // (1024, KDIM) f16 row-major (one dir)
    const float* __restrict__ bias,     // (1024)
    float* __restrict__ out,            // (B*TC, 1024)
    int t_base, int t_sign)
{
    __shared__ uint4 As[2][144];   // [k8][row + row/8] : 8 f16 per entry
    __shared__ uint4 Bs[2][144];
    const int tid = threadIdx.x;
    const int m0 = blockIdx.x * 128;
    const int n0 = blockIdx.y * 128;

    const int lr  = tid & 127;          // loader row
    const int lk8 = tid >> 7;           // 0..1 (k8 within 16-k step)
    const int tcc = (m0 + lr) & (TC - 1);
    const int b   = (m0 + lr) >> TCLOG;
    const int tglob = t_base + t_sign * tcc;
    const long arow = (long)b * SS + tglob;
    const float*  Af = GATHER ? ((const float*)Av + (long)tokens[arow] * KDIM + lk8 * 8) : nullptr;
    const ushort* Ah = GATHER ? nullptr : ((const ushort*)Av + arow * (long)KDIM + lk8 * 8);
    const ushort* Wp = Wh + (long)(n0 + lr) * KDIM + lk8 * 8;
    const int lpad = lr + (lr >> 3);

    const int tr = tid >> 4;            // 0..15 (m octet)
    const int tn = tid & 15;            // 0..15 (n octet)

    float acc[8][8];
    #pragma unroll
    for (int i = 0; i < 8; i++)
        #pragma unroll
        for (int j = 0; j < 8; j++) acc[i][j] = 0.f;

    #pragma unroll 1
    for (int k0 = 0; k0 < KDIM; k0 += 16) {
        uint4 aw, bw;
        if (GATHER) {
            float4 a0 = *(const float4*)(Af + k0);
            float4 a1 = *(const float4*)(Af + k0 + 4);
            aw.x = (uint)f16b(a0.x) | ((uint)f16b(a0.y) << 16);
            aw.y = (uint)f16b(a0.z) | ((uint)f16b(a0.w) << 16);
            aw.z = (uint)f16b(a1.x) | ((uint)f16b(a1.y) << 16);
            aw.w = (uint)f16b(a1.z) | ((uint)f16b(a1.w) << 16);
        } else {
            aw = *(const uint4*)(Ah + k0);
        }
        bw = *(const uint4*)(Wp + k0);
        As[lk8][lpad] = aw;
        Bs[lk8][lpad] = bw;
        __syncthreads();
        #pragma unroll
        for (int k8 = 0; k8 < 2; k8++) {
            uint4 a[8], w[8];
            #pragma unroll
            for (int i = 0; i < 8; i++) {
                a[i] = As[k8][tr * 9 + i];       // rows tr*8+i, padded index
                w[i] = Bs[k8][tn * 9 + i];
            }
            #pragma unroll
            for (int i = 0; i < 8; i++)
                #pragma unroll
                for (int j = 0; j < 8; j++)
                    acc[i][j] = dot8h(w[j], a[i], acc[i][j]);
        }
        __syncthreads();
    }

    float4 bc0 = *(const float4*)(bias + n0 + tn * 8);
    float4 bc1 = *(const float4*)(bias + n0 + tn * 8 + 4);
    #pragma unroll
    for (int i = 0; i < 8; i++) {
        float* op = out + (long)(m0 + tr * 8 + i) * G4 + n0 + tn * 8;
        float4 r0, r1;
        r0.x = acc[i][0] + bc0.x; r0.y = acc[i][1] + bc0.y;
        r0.z = acc[i][2] + bc0.z; r0.w = acc[i][3] + bc0.w;
        r1.x = acc[i][4] + bc1.x; r1.y = acc[i][5] + bc1.y;
        r1.z = acc[i][6] + bc1.z; r1.w = acc[i][7] + bc1.w;
        *(float4*)op = r0;
        *(float4*)(op + 4) = r1;
    }
}

// ---------- int8 LSTM scan v2: 1 barrier/step, wave-local gates ----------
// Thread t: col = t>>2, q = t&3, gate row j = q*256+col — the 4 gate rows of a
// column sit in ADJACENT LANES of one wave. Gates gathered via 4 __shfl, c/h
// computed redundantly in all 4 lanes; only the hq-publish barrier remains.
__global__ __launch_bounds__(1024, 4) void lstm_qscan2(
    const float* __restrict__ xgF, const float* __restrict__ xgB, // [B][TC][1024]
    const uint* __restrict__ wTq,     // [2][16][1024 tidx][4 uint]
    const float* __restrict__ swf,    // [2][1024] by gate row j
    const float* __restrict__ bhh2,   // [2][1024]
    ushort* __restrict__ hout,        // [B*S][512] f16
    float* __restrict__ state,        // [2][B][2][256]
    int tbF, int tbB, int doInit)
{
    const int b = blockIdx.x;
    const int d = blockIdx.y;
    const int t = threadIdx.x;
    const int col = t >> 2, q = t & 3;
    const int j = q * 256 + col;           // gate row
    const float* xg = (d ? xgB : xgF) + (long)b * TC * G4;
    const uint4* wTd = (const uint4*)wTq + (long)d * 16 * 1024;

    __shared__ __align__(16) uint hq[2][64];   // int8 h packed, 256 B each
    __shared__ uint4 lwq[KLQ * 1024];          // 144 KB int8 weight cache

    #pragma unroll
    for (int kc = 0; kc < KLQ; kc++)
        lwq[kc * 1024 + t] = wTd[(long)kc * 1024 + t];

    const float bj  = bhh2[d * G4 + j];
    const float scl = swf[d * G4 + j];
    float c_reg = 0.f, h_reg = 0.f;
    if (!doInit) {
        h_reg = state[((d * BB + b) * 2 + 0) * HH + col];
        c_reg = state[((d * BB + b) * 2 + 1) * HH + col];
    }
    if (q == 0) ((char*)hq[0])[col] = (char)__float2int_rn(h_reg * 127.f);
    __syncthreads();   // covers hq init + lwq fill

    #pragma unroll 1
    for (int tc = 0; tc < TC; ++tc) {
        const int rb = tc & 1;
        const uint4* hc = (const uint4*)hq[rb];   // 16 x uint4 (broadcast)
        int isum = 0;
        #pragma unroll
        for (int kc = 0; kc < KLQ; kc++)
            isum = dot16q(lwq[kc * 1024 + t], hc[kc], isum);
        #pragma unroll
        for (int kc = KLQ; kc < 16; kc++)
            isum = dot16q(wTd[(long)kc * 1024 + t], hc[kc], isum);
        float acc = fmaf((float)isum, scl, xg[(long)tc * G4 + j] + bj);

        // gather the column's 4 gates from adjacent lanes
        const int base = (t & 63) & ~3;
        float gi = __shfl(acc, base + 0);
        float gf = __shfl(acc, base + 1);
        float gg = __shfl(acc, base + 2);
        float go = __shfl(acc, base + 3);
        c_reg = sigf(gf) * c_reg + sigf(gi) * tanhfast(gg);
        float h = sigf(go) * tanhfast(c_reg);
        h_reg = h;
        if (q == 0) ((char*)hq[rb ^ 1])[col] = (char)__float2int_rn(h * 127.f);
        if (q == 1) {
            const int tt = d ? (tbB - tc) : (tbF + tc);
            hout[((long)(b * SS + tt)) * 512 + d * HH + col] = f16b(h);
        }
        __syncthreads();   // hq[rb^1] visible for next step
    }

    if (q == 0) {
        state[((d * BB + b) * 2 + 0) * HH + col] = h_reg;
        state[((d * BB + b) * 2 + 1) * HH + col] = c_reg;
    }
}

// ---------- emissions (f16 h) ----------
__global__ __launch_bounds__(256) void emissions_k16(
    const ushort* __restrict__ h1, const float* __restrict__ clsw,
    const float* __restrict__ clsb, float* __restrict__ em)
{
    long u = (long)blockIdx.x * 256 + threadIdx.x;
    if (u >= (long)BB * SS * NC) return;
    int c = (int)(u % NC);
    long m = u / NC;
    const uint* hr = (const uint*)(h1 + m * 512);
    const float2* wr = (const float2*)(clsw + (long)c * 512);
    float s0 = 0, s1 = 0;
    #pragma unroll 8
    for (int q = 0; q < 256; q += 2) {
        half2v h0 = __builtin_bit_cast(half2v, hr[q]);
        half2v h1v = __builtin_bit_cast(half2v, hr[q + 1]);
        float2 w0 = wr[q], w1 = wr[q + 1];
        s0 += (float)h0.x * w0.x + (float)h0.y * w0.y;
        s1 += (float)h1v.x * w1.x + (float)h1v.y * w1.y;
    }
    em[u] = s0 + s1 + clsb[c];
}

// ---------- CRF log-likelihood per batch row ----------
__global__ __launch_bounds__(64) void crf_llh(
    const float* __restrict__ em, const int* __restrict__ labels,
    const int* __restrict__ mask, const float* __restrict__ start,
    const float* __restrict__ endt, const float* __restrict__ trans,
    float* __restrict__ llh)
{
    int b = blockIdx.x, j = threadIdx.x;
    bool act = j < NC;
    float tcol[NC];
    #pragma unroll
    for (int i = 0; i < NC; i++) tcol[i] = act ? trans[i * NC + j] : 0.f;
    const float* emb_ = em + (long)b * SS * NC;
    const int* lb = labels + b * SS;
    const int* mk = mask + b * SS;
    float alpha = act ? (start[j] + emb_[j]) : -1e30f;

    float num = 0.f;
    int msum = 0;
    for (int t = j; t < SS; t += 64) msum += (mk[t] != 0);
    for (int t = 1 + j; t < SS; t += 64) {
        float m = (float)mk[t];
        num += m * (trans[lb[t - 1] * NC + lb[t]] + emb_[t * NC + lb[t]]);
    }
    for (int o = 32; o > 0; o >>= 1) {
        num  += __shfl_down(num, o);
        msum += __shfl_down(msum, o);
    }
    msum = __shfl(msum, 0);

    for (int t = 1; t < SS; t++) {
        int m = mk[t];
        float emj = act ? emb_[t * NC + j] : 0.f;
        float v[NC];
        float mx = -1e30f;
        #pragma unroll
        for (int i = 0; i < NC; i++) {
            v[i] = __shfl(alpha, i) + tcol[i];
            mx = fmaxf(mx, v[i]);
        }
        float sum = 0.f;
        #pragma unroll
        for (int i = 0; i < NC; i++) sum += __expf(v[i] - mx);
        float nxt = mx + __logf(sum) + emj;
        if (m > 0 && act) alpha = nxt;
    }
    float fin = act ? alpha + endt[j] : -1e30f;
    float mx = -1e30f;
    #pragma unroll
    for (int i = 0; i < NC; i++) mx = fmaxf(mx, __shfl(fin, i));
    float s = 0.f;
    #pragma unroll
    for (int i = 0; i < NC; i++) s += __expf(__shfl(fin, i) - mx);
    float den = mx + __logf(s);
    if (j == 0) {
        int last_idx = msum - 1;
        float numer = num + start[lb[0]] + emb_[lb[0]] + endt[lb[last_idx]];
        llh[b] = numer - den;
    }
}

__global__ __launch_bounds__(64) void loss_k(const float* __restrict__ llh, float* __restrict__ out) {
    int j = threadIdx.x;
    float v = llh[j];
    for (int o = 32; o > 0; o >>= 1) v += __shfl_down(v, o);
    if (j == 0) out[0] = -v / 64.0f;
}

// ---------- Viterbi per batch row ----------
__global__ __launch_bounds__(64) void viterbi_k(
    const float* __restrict__ em, const int* __restrict__ mask,
    const float* __restrict__ start, const float* __restrict__ endt,
    const float* __restrict__ trans, float* __restrict__ outp)
{
    int b = blockIdx.x, j = threadIdx.x;
    bool act = j < NC;
    __shared__ unsigned char bp[SS][NC];
    float tcol[NC];
    #pragma unroll
    for (int i = 0; i < NC; i++) tcol[i] = act ? trans[i * NC + j] : 0.f;
    const float* emb_ = em + (long)b * SS * NC;
    const int* mk = mask + b * SS;
    float score = act ? (start[j] + emb_[j]) : -1e30f;

    for (int t = 1; t < SS; t++) {
        float best = 0.f;
        int bi = 0;
        #pragma unroll
        for (int i = 0; i < NC; i++) {
            float vv = __shfl(score, i) + tcol[i];
            if (i == 0 || vv > best) { best = vv; bi = i; }   // first-max (jnp.argmax)
        }
        int m = mk[t];
        float nxt = best + (act ? emb_[t * NC + j] : 0.f);
        if (act) {
            if (m > 0) { score = nxt; bp[t][j] = (unsigned char)bi; }
            else       { bp[t][j] = (unsigned char)j; }
        }
    }
    float fin = act ? score + endt[j] : -1e30f;
    float bestf = 0.f;
    int last = 0;
    #pragma unroll
    for (int i = 0; i < NC; i++) {
        float vv = __shfl(fin, i);
        if (i == 0 || vv > bestf) { bestf = vv; last = i; }
    }
    __syncthreads();
    if (j == 0) {
        int cur = last;
        outp[1 + (long)b * SS + (SS - 1)] = (float)cur;
        for (int t = SS - 1; t >= 1; t--) {
            cur = bp[t][cur];
            outp[1 + (long)b * SS + (t - 1)] = (float)cur;
        }
    }
}

extern "C" void kernel_launch(void* const* d_in, const int* in_sizes, int n_in,
                              void* d_out, int out_size, void* d_ws, size_t ws_size,
                              hipStream_t stream) {
    const int*   tok    = (const int*)d_in[0];
    const int*   lab    = (const int*)d_in[1];
    const int*   msk    = (const int*)d_in[2];
    const float* emb    = (const float*)d_in[3];
    const float* w_ih0  = (const float*)d_in[4];   // (2,1024,128)
    const float* w_hh0  = (const float*)d_in[5];   // (2,1024,256)
    const float* b_ih0  = (const float*)d_in[6];   // (2,1024)
    const float* b_hh0  = (const float*)d_in[7];
    const float* w_ih1  = (const float*)d_in[8];   // (2,1024,512)
    const float* w_hh1  = (const float*)d_in[9];
    const float* b_ih1  = (const float*)d_in[10];
    const float* b_hh1  = (const float*)d_in[11];
    const float* clsw   = (const float*)d_in[12];  // (9,512)
    const float* clsb   = (const float*)d_in[13];
    const float* startt = (const float*)d_in[14];
    const float* endt   = (const float*)d_in[15];
    const float* transm = (const float*)d_in[16];
    float* out = (float*)d_out;

    // ---- workspace carve (f32 element units); ~140 MB total ----
    size_t nHh  = (size_t)BB * SS * 512 / 2;       // f16 H: 8.39M units each
    size_t nWQ  = (size_t)2 * 16 * 1024 * 16 / 4;  // whh int8
    size_t nSW  = (size_t)2 * 1024;
    size_t nWI0 = (size_t)2048 * 128 / 2;          // w_ih0 f16
    size_t nWI1 = (size_t)2048 * 512 / 2;          // w_ih1 f16
    size_t nEM  = (size_t)BB * SS * NC;
    size_t nST  = (size_t)2 * BB * 2 * HH;
    size_t nXG  = (size_t)BB * TC * G4;            // 8.39M each dir

    float* H0f  = (float*)d_ws;
    float* H1f  = H0f + nHh;
    float* WQ0  = H1f + nHh;
    float* WQ1  = WQ0 + nWQ;
    float* SW0  = WQ1 + nWQ;
    float* SW1  = SW0 + nSW;
    float* WI0  = SW1 + nSW;
    float* WI1  = WI0 + nWI0;
    float* EM   = WI1 + nWI1;
    float* ST   = EM + nEM;
    float* LLH  = ST + nST;
    float* XGF  = LLH + 64;
    float* XGB  = XGF + nXG;

    ushort* H0h = (ushort*)H0f;
    ushort* H1h = (ushort*)H1f;
    ushort* WI0h = (ushort*)WI0;
    ushort* WI1h = (ushort*)WI1;

    quant_whh<<<2048, 64, 0, stream>>>(w_hh0, (uint*)WQ0, SW0);
    quant_whh<<<2048, 64, 0, stream>>>(w_hh1, (uint*)WQ1, SW1);
    pack_f16<<<(2048 * 128 / 8 + 255) / 256, 256, 0, stream>>>(w_ih0, WI0h, 2048 * 128 / 8);
    pack_f16<<<(2048 * 512 / 8 + 255) / 256, 256, 0, stream>>>(w_ih1, WI1h, 2048 * 512 / 8);

    dim3 gg2((BB * TC) / 128, G4 / 128);  // (64, 8)
    dim3 rg(BB, 2);                       // 128 blocks, 1024 threads

    // ---- layer 0 ----
    for (int c = 0; c < NCH; c++) {
        int tbF = c * TC;
        int tbB = SS - 1 - c * TC;
        gemm_xg16b<128, true><<<gg2, 256, 0, stream>>>(emb, tok, WI0h,              b_ih0,        XGF, tbF, +1);
        gemm_xg16b<128, true><<<gg2, 256, 0, stream>>>(emb, tok, WI0h + 1024 * 128, b_ih0 + 1024, XGB, tbB, -1);
        lstm_qscan2<<<rg, 1024, 0, stream>>>(XGF, XGB, (const uint*)WQ0, SW0, b_hh0, H0h, ST, tbF, tbB, c == 0);
    }
    // ---- layer 1 ----
    for (int c = 0; c < NCH; c++) {
        int tbF = c * TC;
        int tbB = SS - 1 - c * TC;
        gemm_xg16b<512, false><<<gg2, 256, 0, stream>>>(H0h, nullptr, WI1h,              b_ih1,        XGF, tbF, +1);
        gemm_xg16b<512, false><<<gg2, 256, 0, stream>>>(H0h, nullptr, WI1h + 1024 * 512, b_ih1 + 1024, XGB, tbB, -1);
        lstm_qscan2<<<rg, 1024, 0, stream>>>(XGF, XGB, (const uint*)WQ1, SW1, b_hh1, H1h, ST, tbF, tbB, c == 0);
    }

    emissions_k16<<<((BB * SS * NC) + 255) / 256, 256, 0, stream>>>(H1h, clsw, clsb, EM);
    crf_llh<<<BB, 64, 0, stream>>>(EM, lab, msk, startt, endt, transm, LLH);
    loss_k<<<1, 64, 0, stream>>>(LLH, out);
    viterbi_k<<<BB, 64, 0, stream>>>(EM, msk, startt, endt, transm, out);
}

// Round 18
// 2480.794 us; speedup vs baseline: 1.1945x; 1.1945x over previous
//
#include <hip/hip_runtime.h>
#include <math.h>

#define BB 64      // batch
#define SS 512     // seq len
#define EE 128     // embed dim
#define HH 256     // hidden
#define NC 9       // classes
#define G4 1024    // 4*H gates (one direction)
#define TCLOG 7
#define TC 128     // time chunk
#define NCH (SS / TC)

#define KLQ 9      // k16 chunks (of 16 k) cached in LDS = 144 KB (int8)
// streamed: kc in [KLQ, 16) = 7 chunks = 112 KB/step

typedef _Float16 half2v __attribute__((ext_vector_type(2)));

// ---------- activations (overflow-safe, fast) ----------
__device__ __forceinline__ float sigf(float x) {
    return 1.0f / (1.0f + __expf(-x));
}
__device__ __forceinline__ float tanhfast(float x) {
    float a = fabsf(x);
    float e = __expf(-2.0f * a);
    float t = (1.0f - e) / (1.0f + e);
    return copysignf(t, x);
}
// 8 f16 MACs via 4x v_dot2_f32_f16 (f32 accumulate)
__device__ __forceinline__ float dot8h(uint4 w, uint4 h, float acc) {
    acc = __builtin_amdgcn_fdot2(__builtin_bit_cast(half2v, w.x),
                                 __builtin_bit_cast(half2v, h.x), acc, false);
    acc = __builtin_amdgcn_fdot2(__builtin_bit_cast(half2v, w.y),
                                 __builtin_bit_cast(half2v, h.y), acc, false);
    acc = __builtin_amdgcn_fdot2(__builtin_bit_cast(half2v, w.z),
                                 __builtin_bit_cast(half2v, h.z), acc, false);
    acc = __builtin_amdgcn_fdot2(__builtin_bit_cast(half2v, w.w),
                                 __builtin_bit_cast(half2v, h.w), acc, false);
    return acc;
}
// 16 i8 MACs via 4x v_dot4_i32_i8 (exact int32 accumulate)
__device__ __forceinline__ int dot16q(uint4 w, uint4 h, int acc) {
    acc = __builtin_amdgcn_sdot4((int)w.x, (int)h.x, acc, false);
    acc = __builtin_amdgcn_sdot4((int)w.y, (int)h.y, acc, false);
    acc = __builtin_amdgcn_sdot4((int)w.z, (int)h.z, acc, false);
    acc = __builtin_amdgcn_sdot4((int)w.w, (int)h.w, acc, false);
    return acc;
}
__device__ __forceinline__ ushort f16b(float x) {
    return __builtin_bit_cast(ushort, (_Float16)x);
}

// ---------- per-row int8 quantize + transpose: w_hh -> wTq[dir][kc][j][16 i8] ----------
// grid 2048 blocks (row = dir*1024+j), 64 threads (1 wave)  [round-16 j-order layout]
__global__ void quant_whh(const float* __restrict__ whh, uint* __restrict__ wTq,
                          float* __restrict__ swf) {
    const int row = blockIdx.x;        // 0..2047
    const int t = threadIdx.x;         // 0..63, owns k = 4t..4t+3
    float4 v = *(const float4*)(whh + (long)row * 256 + t * 4);
    float mx = fmaxf(fmaxf(fabsf(v.x), fabsf(v.y)), fmaxf(fabsf(v.z), fabsf(v.w)));
    #pragma unroll
    for (int o = 32; o > 0; o >>= 1) mx = fmaxf(mx, __shfl_xor(mx, o));
    float inv = (mx > 0.f) ? 127.f / mx : 0.f;
    int q0 = (int)rintf(v.x * inv) & 255;
    int q1 = (int)rintf(v.y * inv) & 255;
    int q2 = (int)rintf(v.z * inv) & 255;
    int q3 = (int)rintf(v.w * inv) & 255;
    uint u = (uint)q0 | ((uint)q1 << 8) | ((uint)q2 << 16) | ((uint)q3 << 24);
    const int dir = row >> 10, j = row & 1023;
    const int kc = t >> 2, l4 = t & 3;
    wTq[(((long)(dir * 16 + kc) * 1024 + j) << 2) + l4] = u;
    if (t == 0) swf[row] = (mx > 0.f) ? (mx / 127.f) * (1.f / 127.f) : 0.f;  // s_w * s_h
}

// ---------- plain f16 pack (row-major, n % 8 == 0) ----------
__global__ void pack_f16(const float* __restrict__ in, ushort* __restrict__ out, int n8) {
    int i = blockIdx.x * 256 + threadIdx.x;
    if (i >= n8) return;
    float4 a = *(const float4*)(in + (long)i * 8);
    float4 b = *(const float4*)(in + (long)i * 8 + 4);
    _Float16 o[8] = {(_Float16)a.x, (_Float16)a.y, (_Float16)a.z, (_Float16)a.w,
                     (_Float16)b.x, (_Float16)b.y, (_Float16)b.z, (_Float16)b.w};
    *(uint4*)(out + (long)i * 8) = *(uint4*)o;
}

// ---------- f16 xg GEMM v2 (round-17 winner): BM=BN=128, 8x8 microtile ----------
template <int KDIM, bool GATHER>
__global__ __launch_bounds__(256, 2) void gemm_xg16b(
    const void* __restrict__ Av, const int* __restrict__ tokens,
    const ushort* __restrict__ Wh,      // (1024, KDIM) f16 row-major (one dir)
    const float* __restrict__ bias,     // (1024)
    float* __restrict__ out,            // (B*TC, 1024)
    int t_base, int t_sign)
{
    __shared__ uint4 As[2][144];   // [k8][row + row/8] : 8 f16 per entry
    __shared__ uint4 Bs[2][144];
    const int tid = threadIdx.x;
    const int m0 = blockIdx.x * 128;
    const int n0 = blockIdx.y * 128;

    const int lr  = tid & 127;          // loader row
    const int lk8 = tid >> 7;           // 0..1 (k8 within 16-k step)
    const int tcc = (m0 + lr) & (TC - 1);
    const int b   = (m0 + lr) >> TCLOG;
    const int tglob = t_base + t_sign * tcc;
    const long arow = (long)b * SS + tglob;
    const float*  Af = GATHER ? ((const float*)Av + (long)tokens[arow] * KDIM + lk8 * 8) : nullptr;
    const ushort* Ah = GATHER ? nullptr : ((const ushort*)Av + arow * (long)KDIM + lk8 * 8);
    const ushort* Wp = Wh + (long)(n0 + lr) * KDIM + lk8 * 8;
    const int lpad = lr + (lr >> 3);

    const int tr = tid >> 4;            // 0..15 (m octet)
    const int tn = tid & 15;            // 0..15 (n octet)

    float acc[8][8];
    #pragma unroll
    for (int i = 0; i < 8; i++)
        #pragma unroll
        for (int j = 0; j < 8; j++) acc[i][j] = 0.f;

    #pragma unroll 1
    for (int k0 = 0; k0 < KDIM; k0 += 16) {
        uint4 aw, bw;
        if (GATHER) {
            float4 a0 = *(const float4*)(Af + k0);
            float4 a1 = *(const float4*)(Af + k0 + 4);
            aw.x = (uint)f16b(a0.x) | ((uint)f16b(a0.y) << 16);
            aw.y = (uint)f16b(a0.z) | ((uint)f16b(a0.w) << 16);
            aw.z = (uint)f16b(a1.x) | ((uint)f16b(a1.y) << 16);
            aw.w = (uint)f16b(a1.z) | ((uint)f16b(a1.w) << 16);
        } else {
            aw = *(const uint4*)(Ah + k0);
        }
        bw = *(const uint4*)(Wp + k0);
        As[lk8][lpad] = aw;
        Bs[lk8][lpad] = bw;
        __syncthreads();
        #pragma unroll
        for (int k8 = 0; k8 < 2; k8++) {
            uint4 a[8], w[8];
            #pragma unroll
            for (int i = 0; i < 8; i++) {
                a[i] = As[k8][tr * 9 + i];       // rows tr*8+i, padded index
                w[i] = Bs[k8][tn * 9 + i];
            }
            #pragma unroll
            for (int i = 0; i < 8; i++)
                #pragma unroll
                for (int j = 0; j < 8; j++)
                    acc[i][j] = dot8h(w[j], a[i], acc[i][j]);
        }
        __syncthreads();
    }

    float4 bc0 = *(const float4*)(bias + n0 + tn * 8);
    float4 bc1 = *(const float4*)(bias + n0 + tn * 8 + 4);
    #pragma unroll
    for (int i = 0; i < 8; i++) {
        float* op = out + (long)(m0 + tr * 8 + i) * G4 + n0 + tn * 8;
        float4 r0, r1;
        r0.x = acc[i][0] + bc0.x; r0.y = acc[i][1] + bc0.y;
        r0.z = acc[i][2] + bc0.z; r0.w = acc[i][3] + bc0.w;
        r1.x = acc[i][4] + bc1.x; r1.y = acc[i][5] + bc1.y;
        r1.z = acc[i][6] + bc1.z; r1.w = acc[i][7] + bc1.w;
        *(float4*)op = r0;
        *(float4*)(op + 4) = r1;
    }
}

// ---------- int8-dot LSTM scan (round-16 proven: 2 barriers, gl exchange) ----------
__global__ __launch_bounds__(1024, 4) void lstm_qscan(
    const float* __restrict__ xgF, const float* __restrict__ xgB, // [B][TC][1024]
    const uint* __restrict__ wTq,     // [2][16][1024][4 uint]
    const float* __restrict__ swf,    // [2][1024] combined scale s_w*s_h
    const float* __restrict__ bhh2,   // [2][1024]
    ushort* __restrict__ hout,        // [B*S][512] f16
    float* __restrict__ state,        // [2][B][2][256]
    int tbF, int tbB, int doInit)
{
    const int b = blockIdx.x;
    const int d = blockIdx.y;
    const int j = threadIdx.x;
    const float* xg = (d ? xgB : xgF) + (long)b * TC * G4 + j;
    const uint4* wTd = (const uint4*)wTq + (long)d * 16 * 1024;

    __shared__ __align__(16) uint hq[2][64];   // int8 h packed, 256 B each
    __shared__ float gl[G4];                   // 4 KB gate exchange
    __shared__ uint4 lwq[KLQ * 1024];          // 144 KB int8 weight cache

    #pragma unroll
    for (int kc = 0; kc < KLQ; kc++)
        lwq[kc * 1024 + j] = wTd[(long)kc * 1024 + j];

    const float bj  = bhh2[d * G4 + j];
    const float scl = swf[d * G4 + j];
    float c_reg = 0.f, h_reg = 0.f;
    if (j < HH) {
        if (!doInit) {
            h_reg = state[((d * BB + b) * 2 + 0) * HH + j];
            c_reg = state[((d * BB + b) * 2 + 1) * HH + j];
        }
        ((char*)hq[0])[j] = (char)__float2int_rn(h_reg * 127.f);
    }
    __syncthreads();   // covers hq init + lwq fill

    #pragma unroll 1
    for (int tc = 0; tc < TC; ++tc) {
        const int rb = tc & 1;
        const uint4* hc = (const uint4*)hq[rb];   // 16 x uint4 (broadcast)
        int isum = 0;

        #pragma unroll
        for (int kc = 0; kc < KLQ; kc++)
            isum = dot16q(lwq[kc * 1024 + j], hc[kc], isum);
        #pragma unroll
        for (int kc = KLQ; kc < 16; kc++)
            isum = dot16q(wTd[(long)kc * 1024 + j], hc[kc], isum);

        gl[j] = fmaf((float)isum, scl, xg[(long)tc * G4] + bj);
        __syncthreads();
        if (j < HH) {
            float gi = gl[j], gf = gl[j + 256], gg = gl[j + 512], go = gl[j + 768];
            c_reg = sigf(gf) * c_reg + sigf(gi) * tanhfast(gg);
            float h = sigf(go) * tanhfast(c_reg);
            h_reg = h;
            ((char*)hq[rb ^ 1])[j] = (char)__float2int_rn(h * 127.f);
            const int t = d ? (tbB - tc) : (tbF + tc);
            hout[((long)(b * SS + t)) * 512 + d * HH + j] = f16b(h);
        }
        __syncthreads();
    }

    if (j < HH) {
        state[((d * BB + b) * 2 + 0) * HH + j] = h_reg;
        state[((d * BB + b) * 2 + 1) * HH + j] = c_reg;
    }
}

// ---------- emissions (f16 h) ----------
__global__ __launch_bounds__(256) void emissions_k16(
    const ushort* __restrict__ h1, const float* __restrict__ clsw,
    const float* __restrict__ clsb, float* __restrict__ em)
{
    long u = (long)blockIdx.x * 256 + threadIdx.x;
    if (u >= (long)BB * SS * NC) return;
    int c = (int)(u % NC);
    long m = u / NC;
    const uint* hr = (const uint*)(h1 + m * 512);
    const float2* wr = (const float2*)(clsw + (long)c * 512);
    float s0 = 0, s1 = 0;
    #pragma unroll 8
    for (int q = 0; q < 256; q += 2) {
        half2v h0 = __builtin_bit_cast(half2v, hr[q]);
        half2v h1v = __builtin_bit_cast(half2v, hr[q + 1]);
        float2 w0 = wr[q], w1 = wr[q + 1];
        s0 += (float)h0.x * w0.x + (float)h0.y * w0.y;
        s1 += (float)h1v.x * w1.x + (float)h1v.y * w1.y;
    }
    em[u] = s0 + s1 + clsb[c];
}

// ---------- CRF log-likelihood per batch row ----------
__global__ __launch_bounds__(64) void crf_llh(
    const float* __restrict__ em, const int* __restrict__ labels,
    const int* __restrict__ mask, const float* __restrict__ start,
    const float* __restrict__ endt, const float* __restrict__ trans,
    float* __restrict__ llh)
{
    int b = blockIdx.x, j = threadIdx.x;
    bool act = j < NC;
    float tcol[NC];
    #pragma unroll
    for (int i = 0; i < NC; i++) tcol[i] = act ? trans[i * NC + j] : 0.f;
    const float* emb_ = em + (long)b * SS * NC;
    const int* lb = labels + b * SS;
    const int* mk = mask + b * SS;
    float alpha = act ? (start[j] + emb_[j]) : -1e30f;

    float num = 0.f;
    int msum = 0;
    for (int t = j; t < SS; t += 64) msum += (mk[t] != 0);
    for (int t = 1 + j; t < SS; t += 64) {
        float m = (float)mk[t];
        num += m * (trans[lb[t - 1] * NC + lb[t]] + emb_[t * NC + lb[t]]);
    }
    for (int o = 32; o > 0; o >>= 1) {
        num  += __shfl_down(num, o);
        msum += __shfl_down(msum, o);
    }
    msum = __shfl(msum, 0);

    for (int t = 1; t < SS; t++) {
        int m = mk[t];
        float emj = act ? emb_[t * NC + j] : 0.f;
        float v[NC];
        float mx = -1e30f;
        #pragma unroll
        for (int i = 0; i < NC; i++) {
            v[i] = __shfl(alpha, i) + tcol[i];
            mx = fmaxf(mx, v[i]);
        }
        float sum = 0.f;
        #pragma unroll
        for (int i = 0; i < NC; i++) sum += __expf(v[i] - mx);
        float nxt = mx + __logf(sum) + emj;
        if (m > 0 && act) alpha = nxt;
    }
    float fin = act ? alpha + endt[j] : -1e30f;
    float mx = -1e30f;
    #pragma unroll
    for (int i = 0; i < NC; i++) mx = fmaxf(mx, __shfl(fin, i));
    float s = 0.f;
    #pragma unroll
    for (int i = 0; i < NC; i++) s += __expf(__shfl(fin, i) - mx);
    float den = mx + __logf(s);
    if (j == 0) {
        int last_idx = msum - 1;
        float numer = num + start[lb[0]] + emb_[lb[0]] + endt[lb[last_idx]];
        llh[b] = numer - den;
    }
}

__global__ __launch_bounds__(64) void loss_k(const float* __restrict__ llh, float* __restrict__ out) {
    int j = threadIdx.x;
    float v = llh[j];
    for (int o = 32; o > 0; o >>= 1) v += __shfl_down(v, o);
    if (j == 0) out[0] = -v / 64.0f;
}

// ---------- Viterbi per batch row ----------
__global__ __launch_bounds__(64) void viterbi_k(
    const float* __restrict__ em, const int* __restrict__ mask,
    const float* __restrict__ start, const float* __restrict__ endt,
    const float* __restrict__ trans, float* __restrict__ outp)
{
    int b = blockIdx.x, j = threadIdx.x;
    bool act = j < NC;
    __shared__ unsigned char bp[SS][NC];
    float tcol[NC];
    #pragma unroll
    for (int i = 0; i < NC; i++) tcol[i] = act ? trans[i * NC + j] : 0.f;
    const float* emb_ = em + (long)b * SS * NC;
    const int* mk = mask + b * SS;
    float score = act ? (start[j] + emb_[j]) : -1e30f;

    for (int t = 1; t < SS; t++) {
        float best = 0.f;
        int bi = 0;
        #pragma unroll
        for (int i = 0; i < NC; i++) {
            float vv = __shfl(score, i) + tcol[i];
            if (i == 0 || vv > best) { best = vv; bi = i; }   // first-max (jnp.argmax)
        }
        int m = mk[t];
        float nxt = best + (act ? emb_[t * NC + j] : 0.f);
        if (act) {
            if (m > 0) { score = nxt; bp[t][j] = (unsigned char)bi; }
            else       { bp[t][j] = (unsigned char)j; }
        }
    }
    float fin = act ? score + endt[j] : -1e30f;
    float bestf = 0.f;
    int last = 0;
    #pragma unroll
    for (int i = 0; i < NC; i++) {
        float vv = __shfl(fin, i);
        if (i == 0 || vv > bestf) { bestf = vv; last = i; }
    }
    __syncthreads();
    if (j == 0) {
        int cur = last;
        outp[1 + (long)b * SS + (SS - 1)] = (float)cur;
        for (int t = SS - 1; t >= 1; t--) {
            cur = bp[t][cur];
            outp[1 + (long)b * SS + (t - 1)] = (float)cur;
        }
    }
}

extern "C" void kernel_launch(void* const* d_in, const int* in_sizes, int n_in,
                              void* d_out, int out_size, void* d_ws, size_t ws_size,
                              hipStream_t stream) {
    const int*   tok    = (const int*)d_in[0];
    const int*   lab    = (const int*)d_in[1];
    const int*   msk    = (const int*)d_in[2];
    const float* emb    = (const float*)d_in[3];
    const float* w_ih0  = (const float*)d_in[4];   // (2,1024,128)
    const float* w_hh0  = (const float*)d_in[5];   // (2,1024,256)
    const float* b_ih0  = (const float*)d_in[6];   // (2,1024)
    const float* b_hh0  = (const float*)d_in[7];
    const float* w_ih1  = (const float*)d_in[8];   // (2,1024,512)
    const float* w_hh1  = (const float*)d_in[9];
    const float* b_ih1  = (const float*)d_in[10];
    const float* b_hh1  = (const float*)d_in[11];
    const float* clsw   = (const float*)d_in[12];  // (9,512)
    const float* clsb   = (const float*)d_in[13];
    const float* startt = (const float*)d_in[14];
    const float* endt   = (const float*)d_in[15];
    const float* transm = (const float*)d_in[16];
    float* out = (float*)d_out;

    // ---- workspace carve (f32 element units); ~140 MB total ----
    size_t nHh  = (size_t)BB * SS * 512 / 2;       // f16 H: 8.39M units each
    size_t nWQ  = (size_t)2 * 16 * 1024 * 16 / 4;  // whh int8
    size_t nSW  = (size_t)2 * 1024;
    size_t nWI0 = (size_t)2048 * 128 / 2;          // w_ih0 f16
    size_t nWI1 = (size_t)2048 * 512 / 2;          // w_ih1 f16
    size_t nEM  = (size_t)BB * SS * NC;
    size_t nST  = (size_t)2 * BB * 2 * HH;
    size_t nXG  = (size_t)BB * TC * G4;            // 8.39M each dir

    float* H0f  = (float*)d_ws;
    float* H1f  = H0f + nHh;
    float* WQ0  = H1f + nHh;
    float* WQ1  = WQ0 + nWQ;
    float* SW0  = WQ1 + nWQ;
    float* SW1  = SW0 + nSW;
    float* WI0  = SW1 + nSW;
    float* WI1  = WI0 + nWI0;
    float* EM   = WI1 + nWI1;
    float* ST   = EM + nEM;
    float* LLH  = ST + nST;
    float* XGF  = LLH + 64;
    float* XGB  = XGF + nXG;

    ushort* H0h = (ushort*)H0f;
    ushort* H1h = (ushort*)H1f;
    ushort* WI0h = (ushort*)WI0;
    ushort* WI1h = (ushort*)WI1;

    quant_whh<<<2048, 64, 0, stream>>>(w_hh0, (uint*)WQ0, SW0);
    quant_whh<<<2048, 64, 0, stream>>>(w_hh1, (uint*)WQ1, SW1);
    pack_f16<<<(2048 * 128 / 8 + 255) / 256, 256, 0, stream>>>(w_ih0, WI0h, 2048 * 128 / 8);
    pack_f16<<<(2048 * 512 / 8 + 255) / 256, 256, 0, stream>>>(w_ih1, WI1h, 2048 * 512 / 8);

    dim3 gg2((BB * TC) / 128, G4 / 128);  // (64, 8)
    dim3 rg(BB, 2);                       // 128 blocks, 1024 threads

    // ---- layer 0 ----
    for (int c = 0; c < NCH; c++) {
        int tbF = c * TC;
        int tbB = SS - 1 - c * TC;
        gemm_xg16b<128, true><<<gg2, 256, 0, stream>>>(emb, tok, WI0h,              b_ih0,        XGF, tbF, +1);
        gemm_xg16b<128, true><<<gg2, 256, 0, stream>>>(emb, tok, WI0h + 1024 * 128, b_ih0 + 1024, XGB, tbB, -1);
        lstm_qscan<<<rg, 1024, 0, stream>>>(XGF, XGB, (const uint*)WQ0, SW0, b_hh0, H0h, ST, tbF, tbB, c == 0);
    }
    // ---- layer 1 ----
    for (int c = 0; c < NCH; c++) {
        int tbF = c * TC;
        int tbB = SS - 1 - c * TC;
        gemm_xg16b<512, false><<<gg2, 256, 0, stream>>>(H0h, nullptr, WI1h,              b_ih1,        XGF, tbF, +1);
        gemm_xg16b<512, false><<<gg2, 256, 0, stream>>>(H0h, nullptr, WI1h + 1024 * 512, b_ih1 + 1024, XGB, tbB, -1);
        lstm_qscan<<<rg, 1024, 0, stream>>>(XGF, XGB, (const uint*)WQ1, SW1, b_hh1, H1h, ST, tbF, tbB, c == 0);
    }

    emissions_k16<<<((BB * SS * NC) + 255) / 256, 256, 0, stream>>>(H1h, clsw, clsb, EM);
    crf_llh<<<BB, 64, 0, stream>>>(EM, lab, msk, startt, endt, transm, LLH);
    loss_k<<<1, 64, 0, stream>>>(LLH, out);
    viterbi_k<<<BB, 64, 0, stream>>>(EM, msk, startt, endt, transm, out);
}